// Round 5
// baseline (457.659 us; speedup 1.0000x reference)
//
#include <hip/hip_runtime.h>
#include <math.h>

#define NB   8
#define NC   256
#define ND   64
#define NPIX 4096
#define LSTR 72   // attn P LDS row stride (bf16 elems)

typedef short bf16x8 __attribute__((ext_vector_type(8)));   // 8 bf16 (4 VGPRs)
typedef float f32x4  __attribute__((ext_vector_type(4)));
typedef float f32x16 __attribute__((ext_vector_type(16)));

static __device__ __forceinline__ ushort f2bf(float f) {
    uint u = __float_as_uint(f);
    u += 0x7fffu + ((u >> 16) & 1u);      // round-to-nearest-even
    return (ushort)(u >> 16);
}
static __device__ __forceinline__ float bf2f(ushort h) {
    return __uint_as_float(((uint)h) << 16);
}

// ---------------------------------------------------------------------------
// transpose_x: x[b][c][p] f32 -> xt_h/xt_l [b][p][256] bf16 hi/lo.
// ---------------------------------------------------------------------------
__global__ __launch_bounds__(256) void transpose_x(
    const float* __restrict__ x, ushort* __restrict__ xth, ushort* __restrict__ xtl)
{
    __shared__ float tile[64][68];
    const int t = threadIdx.x;
    const int p0 = blockIdx.x * 64, c0 = blockIdx.y * 64, b = blockIdx.z;

    const int cl = t >> 4, p4 = (t & 15) * 4;
    #pragma unroll
    for (int i = 0; i < 4; i++) {
        const int c = cl + 16 * i;
        *(float4*)&tile[c][p4] =
            *(const float4*)&x[((size_t)(b * NC + c0 + c)) * NPIX + p0 + p4];
    }
    __syncthreads();

    const int pl = t & 63, ch = t >> 6;
    float v[16];
    #pragma unroll
    for (int j = 0; j < 16; j++) v[j] = tile[ch * 16 + j][pl];
    ushort h[16], l[16];
    #pragma unroll
    for (int j = 0; j < 16; j++) {
        h[j] = f2bf(v[j]);
        l[j] = f2bf(v[j] - bf2f(h[j]));
    }
    const size_t o = ((size_t)(b * NPIX + p0 + pl)) * 256 + c0 + ch * 16;
    *(uint4*)&xth[o]     = *(uint4*)&h[0];
    *(uint4*)&xth[o + 8] = *(uint4*)&h[8];
    *(uint4*)&xtl[o]     = *(uint4*)&l[0];
    *(uint4*)&xtl[o + 8] = *(uint4*)&l[8];
}

// ---------------------------------------------------------------------------
// transpose_w: W[co][ci][3][3] f32 -> wt[rs][co][ci] bf16 (hi/lo for q,k).
// ---------------------------------------------------------------------------
__global__ __launch_bounds__(256) void transpose_w(
    const float* __restrict__ Wq, const float* __restrict__ Wk,
    const float* __restrict__ Wv,
    ushort* __restrict__ qh, ushort* __restrict__ ql,
    ushort* __restrict__ kh, ushort* __restrict__ kl,
    ushort* __restrict__ vh)
{
    __shared__ float wb[2304];
    const int g = blockIdx.x, t = threadIdx.x;
    const float* src;
    ushort *dh, *dl;
    int co, Co, split;
    if (g < 64)       { src = Wq + (size_t)g * 2304; co = g;       Co = 64;  dh = qh; dl = ql; split = 1; }
    else if (g < 128) { src = Wk + (size_t)(g - 64) * 2304; co = g - 64; Co = 64; dh = kh; dl = kl; split = 1; }
    else              { src = Wv + (size_t)(g - 128) * 2304; co = g - 128; Co = 256; dh = vh; dl = nullptr; split = 0; }

    for (int i = t; i < 2304; i += 256) wb[i] = src[i];
    __syncthreads();
    for (int j = t; j < 2304; j += 256) {
        const int rs = j >> 8, ci = j & 255;
        const float v = wb[ci * 9 + rs];
        const ushort hv = f2bf(v);
        const size_t o = ((size_t)(rs * Co + co)) * 256 + ci;
        dh[o] = hv;
        if (split) dl[o] = f2bf(v - bf2f(hv));
    }
}

// ---------------------------------------------------------------------------
// conv q/k (split-bf16 3-term, single pass). Block 64co x 256pix, wave=h-row.
// x (hi+lo) and w (hi+lo) single-buffered in LDS, register-prefetched.
// grid (16 hq, 8 b, 2 {q,k}). LDS 75136 B static.
// ---------------------------------------------------------------------------
__global__ __launch_bounds__(256, 2) void conv_qk_k(
    const ushort* __restrict__ xth, const ushort* __restrict__ xtl,
    const ushort* __restrict__ wqh, const ushort* __restrict__ wql,
    const ushort* __restrict__ wkh, const ushort* __restrict__ wkl,
    const float* __restrict__ bq, const float* __restrict__ bk,
    ushort* __restrict__ qoh, ushort* __restrict__ qol,
    ushort* __restrict__ koh, ushort* __restrict__ kol)
{
    __shared__ ushort xs[2][6 * 66 * 24];   // [plane hi/lo][row][col][ci pad24]
    __shared__ ushort ws[9 * 2 * 64 * 16];  // [rs][hl][co][16ci]
    __shared__ float  sbias[64];

    const int hq = blockIdx.x, b = blockIdx.y, ct = blockIdx.z;
    const ushort* wth = ct ? wkh : wqh;
    const ushort* wtl = ct ? wkl : wql;
    const float*  bias = ct ? bk : bq;
    ushort* outh = ct ? koh : qoh;
    ushort* outl = ct ? kol : qol;

    const int t = threadIdx.x;
    const int wv = t >> 6, lane = t & 63;
    const int l31 = lane & 31, khl = lane >> 5;
    const int h = hq * 4 + wv;

    if (t < 64) sbias[t] = bias[t];
    // zero halo cols 0 and 65 (rows 0..5, ci 0..15, both planes) — never overwritten
    for (int i = t; i < 384; i += 256) {
        const int p = i / 192, r2 = i % 192;
        const int row = r2 / 32, e = (r2 % 32) / 16, ci = r2 & 15;
        xs[p][(row * 66 + e * 65) * 24 + ci] = 0;
    }

    // staging decompositions
    int s_cih[3], s_col[3], s_row[3], s_hs[3];
    #pragma unroll
    for (int i = 0; i < 3; i++) {
        const int a = i * 256 + t;
        s_cih[i] = a & 1; s_col[i] = (a >> 1) & 63; s_row[i] = a >> 7;
        s_hs[i] = hq * 4 + s_row[i] - 1;
    }
    int w_cih[9], w_co[9], w_hl[9], w_rs[9];
    #pragma unroll
    for (int i = 0; i < 9; i++) {
        const int a = i * 256 + t;
        w_cih[i] = a & 1; w_co[i] = (a >> 1) & 63; w_hl[i] = (a >> 7) & 1; w_rs[i] = a >> 8;
    }

    uint4 xr[6], wr[9];
    // preload chunk 0
    #pragma unroll
    for (int i = 0; i < 3; i++) {
        uint4 vh = {0,0,0,0}, vl = {0,0,0,0};
        if (s_hs[i] >= 0 && s_hs[i] < 64) {
            const size_t g = ((size_t)(b * NPIX + s_hs[i] * 64 + s_col[i])) * 256 + s_cih[i] * 8;
            vh = *(const uint4*)&xth[g];
            vl = *(const uint4*)&xtl[g];
        }
        xr[i] = vh; xr[3 + i] = vl;
    }
    #pragma unroll
    for (int i = 0; i < 9; i++) {
        const ushort* wsrc = w_hl[i] ? wtl : wth;
        wr[i] = *(const uint4*)&wsrc[((size_t)(w_rs[i] * 64 + w_co[i])) * 256 + w_cih[i] * 8];
    }

    f32x16 a00 = {0}, a01 = {0}, a10 = {0}, a11 = {0};  // [ms(co)][ns(pix)]
    const int wAbase = l31 * 16 + khl * 8;
    const int xBbase = khl * 8;

    for (int ch = 0; ch < 16; ch++) {
        // write staged regs -> LDS
        #pragma unroll
        for (int i = 0; i < 3; i++) {
            const int o = (s_row[i] * 66 + 1 + s_col[i]) * 24 + s_cih[i] * 8;
            *(uint4*)&xs[0][o] = xr[i];
            *(uint4*)&xs[1][o] = xr[3 + i];
        }
        #pragma unroll
        for (int i = 0; i < 9; i++)
            *(uint4*)&ws[((w_rs[i] * 2 + w_hl[i]) * 64 + w_co[i]) * 16 + w_cih[i] * 8] = wr[i];
        __syncthreads();

        // prefetch next chunk
        if (ch < 15) {
            const int ci1 = (ch + 1) * 16;
            #pragma unroll
            for (int i = 0; i < 3; i++) {
                uint4 vh = {0,0,0,0}, vl = {0,0,0,0};
                if (s_hs[i] >= 0 && s_hs[i] < 64) {
                    const size_t g = ((size_t)(b * NPIX + s_hs[i] * 64 + s_col[i])) * 256 + ci1 + s_cih[i] * 8;
                    vh = *(const uint4*)&xth[g];
                    vl = *(const uint4*)&xtl[g];
                }
                xr[i] = vh; xr[3 + i] = vl;
            }
            #pragma unroll
            for (int i = 0; i < 9; i++) {
                const ushort* wsrc = w_hl[i] ? wtl : wth;
                wr[i] = *(const uint4*)&wsrc[((size_t)(w_rs[i] * 64 + w_co[i])) * 256 + ci1 + w_cih[i] * 8];
            }
        }

        // compute: 9 taps x 12 MFMA (wh.xh, wl.xh, wh.xl)
        #pragma unroll
        for (int rs = 0; rs < 9; rs++) {
            const int r = rs / 3, s = rs % 3;
            bf16x8 A0h = *(const bf16x8*)&ws[(rs * 2 + 0) * 1024 + wAbase];
            bf16x8 A1h = *(const bf16x8*)&ws[(rs * 2 + 0) * 1024 + 512 + wAbase];
            bf16x8 A0l = *(const bf16x8*)&ws[(rs * 2 + 1) * 1024 + wAbase];
            bf16x8 A1l = *(const bf16x8*)&ws[(rs * 2 + 1) * 1024 + 512 + wAbase];
            const int xo = ((wv + r) * 66 + s + l31) * 24 + xBbase;
            bf16x8 B0h = *(const bf16x8*)&xs[0][xo];
            bf16x8 B1h = *(const bf16x8*)&xs[0][xo + 768];
            bf16x8 B0l = *(const bf16x8*)&xs[1][xo];
            bf16x8 B1l = *(const bf16x8*)&xs[1][xo + 768];
            a00 = __builtin_amdgcn_mfma_f32_32x32x16_bf16(A0h, B0h, a00, 0, 0, 0);
            a01 = __builtin_amdgcn_mfma_f32_32x32x16_bf16(A0h, B1h, a01, 0, 0, 0);
            a10 = __builtin_amdgcn_mfma_f32_32x32x16_bf16(A1h, B0h, a10, 0, 0, 0);
            a11 = __builtin_amdgcn_mfma_f32_32x32x16_bf16(A1h, B1h, a11, 0, 0, 0);
            a00 = __builtin_amdgcn_mfma_f32_32x32x16_bf16(A0l, B0h, a00, 0, 0, 0);
            a01 = __builtin_amdgcn_mfma_f32_32x32x16_bf16(A0l, B1h, a01, 0, 0, 0);
            a10 = __builtin_amdgcn_mfma_f32_32x32x16_bf16(A1l, B0h, a10, 0, 0, 0);
            a11 = __builtin_amdgcn_mfma_f32_32x32x16_bf16(A1l, B1h, a11, 0, 0, 0);
            a00 = __builtin_amdgcn_mfma_f32_32x32x16_bf16(A0h, B0l, a00, 0, 0, 0);
            a01 = __builtin_amdgcn_mfma_f32_32x32x16_bf16(A0h, B1l, a01, 0, 0, 0);
            a10 = __builtin_amdgcn_mfma_f32_32x32x16_bf16(A1h, B0l, a10, 0, 0, 0);
            a11 = __builtin_amdgcn_mfma_f32_32x32x16_bf16(A1h, B1l, a11, 0, 0, 0);
        }
        __syncthreads();   // compute done before next write
    }

    // epilogue: C/D col = pixel, row = co = (reg&3)+8*(reg>>2)+4*khl
    const float4* sb4 = (const float4*)sbias;
    #pragma unroll
    for (int ms = 0; ms < 2; ms++)
        #pragma unroll
        for (int ns = 0; ns < 2; ns++) {
            const f32x16 av = ms ? (ns ? a11 : a10) : (ns ? a01 : a00);
            const int p = h * 64 + ns * 32 + l31;
            #pragma unroll
            for (int g = 0; g < 4; g++) {
                const float4 bi = sb4[ms * 8 + 2 * g + khl];
                float v0 = av[4 * g + 0] + bi.x;
                float v1 = av[4 * g + 1] + bi.y;
                float v2 = av[4 * g + 2] + bi.z;
                float v3 = av[4 * g + 3] + bi.w;
                ushort4 hv, lv;
                hv.x = f2bf(v0); lv.x = f2bf(v0 - bf2f(hv.x));
                hv.y = f2bf(v1); lv.y = f2bf(v1 - bf2f(hv.y));
                hv.z = f2bf(v2); lv.z = f2bf(v2 - bf2f(hv.z));
                hv.w = f2bf(v3); lv.w = f2bf(v3 - bf2f(hv.w));
                const size_t o = ((size_t)(b * NPIX + p)) * 64 + ms * 32 + 8 * g + 4 * khl;
                *(ushort4*)&outh[o] = hv;
                *(ushort4*)&outl[o] = lv;
            }
        }
}

// ---------------------------------------------------------------------------
// conv v (plain bf16). A = x (m=pixel), B = w (n=co). x,w single-buffered LDS,
// register-prefetched. grid (16 hq, 8 b, 4 cotile). LDS 37.7 KB static.
// ---------------------------------------------------------------------------
__global__ __launch_bounds__(256, 2) void conv_v_k(
    const ushort* __restrict__ xth, const ushort* __restrict__ wtv,
    const float* __restrict__ bv, ushort* __restrict__ vout)
{
    __shared__ ushort xs[6 * 66 * 24];
    __shared__ ushort ws[9 * 64 * 16];
    __shared__ float  sbias[64];

    const int hq = blockIdx.x, b = blockIdx.y, co0 = blockIdx.z * 64;
    const int t = threadIdx.x;
    const int wv = t >> 6, lane = t & 63;
    const int l31 = lane & 31, khl = lane >> 5;
    const int h = hq * 4 + wv;

    if (t < 64) sbias[t] = bv[co0 + t];
    for (int i = t; i < 192; i += 256) {
        const int row = i / 32, e = (i % 32) / 16, ci = i & 15;
        xs[(row * 66 + e * 65) * 24 + ci] = 0;
    }

    int s_cih[3], s_col[3], s_row[3], s_hs[3];
    #pragma unroll
    for (int i = 0; i < 3; i++) {
        const int a = i * 256 + t;
        s_cih[i] = a & 1; s_col[i] = (a >> 1) & 63; s_row[i] = a >> 7;
        s_hs[i] = hq * 4 + s_row[i] - 1;
    }
    int w_cih[5], w_co[5], w_rs[5], w_ok[5];
    #pragma unroll
    for (int i = 0; i < 5; i++) {
        const int a = i * 256 + t;
        w_ok[i] = a < 1152;
        const int aa = w_ok[i] ? a : 0;
        w_cih[i] = aa & 1; w_co[i] = (aa >> 1) & 63; w_rs[i] = aa >> 7;
    }

    uint4 xr[3], wr[5];
    #pragma unroll
    for (int i = 0; i < 3; i++) {
        uint4 vh = {0,0,0,0};
        if (s_hs[i] >= 0 && s_hs[i] < 64)
            vh = *(const uint4*)&xth[((size_t)(b * NPIX + s_hs[i] * 64 + s_col[i])) * 256 + s_cih[i] * 8];
        xr[i] = vh;
    }
    #pragma unroll
    for (int i = 0; i < 5; i++)
        if (w_ok[i])
            wr[i] = *(const uint4*)&wtv[((size_t)(w_rs[i] * 256 + co0 + w_co[i])) * 256 + w_cih[i] * 8];

    f32x16 a00 = {0}, a01 = {0}, a10 = {0}, a11 = {0};  // [ms(pix)][ns(co)]
    const int wBbase = l31 * 16 + khl * 8;
    const int xAbase = khl * 8;

    for (int ch = 0; ch < 16; ch++) {
        #pragma unroll
        for (int i = 0; i < 3; i++)
            *(uint4*)&xs[(s_row[i] * 66 + 1 + s_col[i]) * 24 + s_cih[i] * 8] = xr[i];
        #pragma unroll
        for (int i = 0; i < 5; i++)
            if (w_ok[i])
                *(uint4*)&ws[(w_rs[i] * 64 + w_co[i]) * 16 + w_cih[i] * 8] = wr[i];
        __syncthreads();

        if (ch < 15) {
            const int ci1 = (ch + 1) * 16;
            #pragma unroll
            for (int i = 0; i < 3; i++) {
                uint4 vh = {0,0,0,0};
                if (s_hs[i] >= 0 && s_hs[i] < 64)
                    vh = *(const uint4*)&xth[((size_t)(b * NPIX + s_hs[i] * 64 + s_col[i])) * 256 + ci1 + s_cih[i] * 8];
                xr[i] = vh;
            }
            #pragma unroll
            for (int i = 0; i < 5; i++)
                if (w_ok[i])
                    wr[i] = *(const uint4*)&wtv[((size_t)(w_rs[i] * 256 + co0 + w_co[i])) * 256 + ci1 + w_cih[i] * 8];
        }

        #pragma unroll
        for (int rs = 0; rs < 9; rs++) {
            const int r = rs / 3, s = rs % 3;
            const int xo = ((wv + r) * 66 + s + l31) * 24 + xAbase;
            bf16x8 A0 = *(const bf16x8*)&xs[xo];
            bf16x8 A1 = *(const bf16x8*)&xs[xo + 768];
            bf16x8 B0 = *(const bf16x8*)&ws[rs * 1024 + wBbase];
            bf16x8 B1 = *(const bf16x8*)&ws[rs * 1024 + 512 + wBbase];
            a00 = __builtin_amdgcn_mfma_f32_32x32x16_bf16(A0, B0, a00, 0, 0, 0);
            a01 = __builtin_amdgcn_mfma_f32_32x32x16_bf16(A0, B1, a01, 0, 0, 0);
            a10 = __builtin_amdgcn_mfma_f32_32x32x16_bf16(A1, B0, a10, 0, 0, 0);
            a11 = __builtin_amdgcn_mfma_f32_32x32x16_bf16(A1, B1, a11, 0, 0, 0);
        }
        __syncthreads();
    }

    // epilogue: C/D col = co (l31), row = pixel = (reg&3)+8*(reg>>2)+4*khl
    #pragma unroll
    for (int ns = 0; ns < 2; ns++) {
        const int co = co0 + ns * 32 + l31;
        const float bi = sbias[ns * 32 + l31];
        #pragma unroll
        for (int ms = 0; ms < 2; ms++) {
            const f32x16 av = ms ? (ns ? a11 : a10) : (ns ? a01 : a00);
            #pragma unroll
            for (int g = 0; g < 4; g++) {
                const int p = h * 64 + ms * 32 + 8 * g + 4 * khl;
                ushort4 ov;
                ov.x = f2bf(av[4 * g + 0] + bi);
                ov.y = f2bf(av[4 * g + 1] + bi);
                ov.z = f2bf(av[4 * g + 2] + bi);
                ov.w = f2bf(av[4 * g + 3] + bi);
                *(ushort4*)&vout[((size_t)(b * NC + co)) * NPIX + p] = ov;
            }
        }
    }
}

// ---------------------------------------------------------------------------
// MFMA flash attention v3. grid 512 1-D (b = id&7 -> XCD pin), block 256.
// S^T = K.Q^T (A=K frags direct from global, nt-partitioned per wave;
// B=Q frags hoisted). P -> LDS via one ds_write_b64 per tile (C-layout rows
// = consecutive n). PV: V frags direct from global (c-partitioned), P frags
// from LDS in A-layout b128. Rowsums in registers from rounded P.
// LDS ~10.5 KB. 2 barriers/iter.
// ---------------------------------------------------------------------------
__global__ __launch_bounds__(256, 2) void attn_k(
    const ushort* __restrict__ qh, const ushort* __restrict__ ql,
    const ushort* __restrict__ kh, const ushort* __restrict__ kl,
    const ushort* __restrict__ vb, const float* __restrict__ x,
    float* __restrict__ out)
{
    const int id = blockIdx.x;
    const int b  = id & 7;
    const int m0 = (id >> 3) * 64;
    const int t  = threadIdx.x;
    const int w  = t >> 6;
    const int lane = t & 63;
    const int quad = lane >> 4;
    const int l16  = lane & 15;

    __shared__ ushort sps[64 * LSTR];   // P [m][n-within-tile]
    __shared__ float  red[4][64];
    __shared__ float  ivl[64];

    // hoisted Q B-frags: B[col=m=l16][k=d]
    bf16x8 aqh[4][2], aql[4][2];
    #pragma unroll
    for (int mg = 0; mg < 4; mg++)
        #pragma unroll
        for (int ks = 0; ks < 2; ks++) {
            const size_t g = ((size_t)b * NPIX + m0 + mg * 16 + l16) * ND + ks * 32 + quad * 8;
            aqh[mg][ks] = *(const bf16x8*)&qh[g];
            aql[mg][ks] = *(const bf16x8*)&ql[g];
        }

    f32x4 acc[4][4];
    #pragma unroll
    for (int i = 0; i < 4; i++)
        #pragma unroll
        for (int j = 0; j < 4; j++) acc[i][j] = (f32x4){0.f, 0.f, 0.f, 0.f};
    float lsum[4] = {0.f, 0.f, 0.f, 0.f};

    for (int n0 = 0; n0 < NPIX; n0 += 64) {
        // K A-frags for this wave's nt = w (direct global, no redundancy)
        bf16x8 kfh[2], kfl[2];
        #pragma unroll
        for (int ks = 0; ks < 2; ks++) {
            const size_t g = ((size_t)b * NPIX + n0 + 16 * w + l16) * ND + ks * 32 + quad * 8;
            kfh[ks] = *(const bf16x8*)&kh[g];
            kfl[ks] = *(const bf16x8*)&kl[g];
        }
        // V B-frags for this wave's c-slice (direct global)
        bf16x8 vf[4][2];
        #pragma unroll
        for (int ct = 0; ct < 4; ct++)
            #pragma unroll
            for (int ks = 0; ks < 2; ks++) {
                const int c = 64 * w + ct * 16 + l16;
                vf[ct][ks] = *(const bf16x8*)&vb[((size_t)b * NC + c) * NPIX + n0 + ks * 32 + quad * 8];
            }

        // S^T = K.Q^T, exp, pack 4 consecutive-n bf16 -> one b64 store
        #pragma unroll
        for (int mg = 0; mg < 4; mg++) {
            f32x4 s = {0.f, 0.f, 0.f, 0.f};
            #pragma unroll
            for (int ks = 0; ks < 2; ks++) {
                s = __builtin_amdgcn_mfma_f32_16x16x32_bf16(kfh[ks], aqh[mg][ks], s, 0, 0, 0);
                s = __builtin_amdgcn_mfma_f32_16x16x32_bf16(kfl[ks], aqh[mg][ks], s, 0, 0, 0);
                s = __builtin_amdgcn_mfma_f32_16x16x32_bf16(kfh[ks], aql[mg][ks], s, 0, 0, 0);
            }
            uint2 pk;
            float ss = 0.f;
            {
                const ushort p0 = f2bf(__expf(s[0] - 30.f));
                const ushort p1 = f2bf(__expf(s[1] - 30.f));
                const ushort p2 = f2bf(__expf(s[2] - 30.f));
                const ushort p3 = f2bf(__expf(s[3] - 30.f));
                ss = (bf2f(p0) + bf2f(p1)) + (bf2f(p2) + bf2f(p3));
                pk.x = (uint)p0 | ((uint)p1 << 16);
                pk.y = (uint)p2 | ((uint)p3 << 16);
            }
            lsum[mg] += ss;
            *(uint2*)&sps[(mg * 16 + l16) * LSTR + 16 * w + quad * 4] = pk;
        }
        __syncthreads();   // P visible

        // PV: A = P frags (LDS), B = V frags (regs)
        #pragma unroll
        for (int ks = 0; ks < 2; ks++) {
            bf16x8 ap[4];
            #pragma unroll
            for (int mg = 0; mg < 4; mg++)
                ap[mg] = *(const bf16x8*)&sps[(mg * 16 + l16) * LSTR + ks * 32 + quad * 8];
            #pragma unroll
            for (int mg = 0; mg < 4; mg++)
                #pragma unroll
                for (int ct = 0; ct < 4; ct++)
                    acc[mg][ct] = __builtin_amdgcn_mfma_f32_16x16x32_bf16(
                        ap[mg], vf[ct][ks], acc[mg][ct], 0, 0, 0);
        }
        __syncthreads();   // P reads done before next iter's writes
    }

    // rowsum: reduce across quad lanes, then across the 4 nt-waves via LDS
    #pragma unroll
    for (int mg = 0; mg < 4; mg++) {
        lsum[mg] += __shfl_xor(lsum[mg], 16, 64);
        lsum[mg] += __shfl_xor(lsum[mg], 32, 64);
    }
    if (quad == 0) {
        #pragma unroll
        for (int mg = 0; mg < 4; mg++) red[w][mg * 16 + l16] = lsum[mg];
    }
    __syncthreads();
    if (t < 64)
        ivl[t] = 1.f / (red[0][t] + red[1][t] + red[2][t] + red[3][t]);
    __syncthreads();

    // epilogue: out = acc/l + x; D rows m = mg*16+quad*4+r, col c = l16
    #pragma unroll
    for (int mg = 0; mg < 4; mg++) {
        const int mrow = mg * 16 + quad * 4;
        const float4 il4 = *(const float4*)&ivl[mrow];
        const int m = m0 + mrow;
        #pragma unroll
        for (int ct = 0; ct < 4; ct++) {
            const int c = 64 * w + ct * 16 + l16;
            const size_t base = ((size_t)b * NC + c) * NPIX + m;
            const float4 xv = *(const float4*)&x[base];
            const f32x4 a = acc[mg][ct];
            float4 o;
            o.x = fmaf(a[0], il4.x, xv.x);
            o.y = fmaf(a[1], il4.y, xv.y);
            o.z = fmaf(a[2], il4.z, xv.z);
            o.w = fmaf(a[3], il4.w, xv.w);
            *(float4*)&out[base] = o;
        }
    }
}

extern "C" void kernel_launch(void* const* d_in, const int* in_sizes, int n_in,
                              void* d_out, int out_size, void* d_ws, size_t ws_size,
                              hipStream_t stream)
{
    const float* x  = (const float*)d_in[0];
    const float* Wq = (const float*)d_in[1];
    const float* bq = (const float*)d_in[2];
    const float* Wk = (const float*)d_in[3];
    const float* bk = (const float*)d_in[4];
    const float* Wv = (const float*)d_in[5];
    const float* bv = (const float*)d_in[6];
    float* outp = (float*)d_out;

    const size_t XT = (size_t)NB * NPIX * 256;   // 8,388,608
    const size_t QK = (size_t)NB * NPIX * ND;    // 2,097,152
    ushort* xt_h = (ushort*)d_ws;
    ushort* xt_l = xt_h + XT;
    ushort* v_b  = xt_l;              // alias: conv_v (after conv_qk) overwrites xt_l
    ushort* q_h  = xt_l + XT;
    ushort* q_l  = q_h + QK;
    ushort* k_h  = q_l + QK;
    ushort* k_l  = k_h + QK;
    ushort* wtq_h = k_l + QK;         // 9*64*256 = 147456 each
    ushort* wtq_l = wtq_h + 147456;
    ushort* wtk_h = wtq_l + 147456;
    ushort* wtk_l = wtk_h + 147456;
    ushort* wtv_h = wtk_l + 147456;   // 9*256*256 = 589824

    dim3 blk(256);
    transpose_x<<<dim3(64, 4, NB), blk, 0, stream>>>(x, xt_h, xt_l);
    transpose_w<<<dim3(384), blk, 0, stream>>>(Wq, Wk, Wv, wtq_h, wtq_l, wtk_h, wtk_l, wtv_h);
    conv_qk_k<<<dim3(16, NB, 2), blk, 0, stream>>>(
        xt_h, xt_l, wtq_h, wtq_l, wtk_h, wtk_l, bq, bk, q_h, q_l, k_h, k_l);
    conv_v_k<<<dim3(16, NB, 4), blk, 0, stream>>>(xt_h, wtv_h, bv, v_b);
    attn_k<<<dim3(512), blk, 0, stream>>>(q_h, q_l, k_h, k_l, v_b, x, outp);
}

// Round 6
// 425.138 us; speedup vs baseline: 1.0765x; 1.0765x over previous
//
#include <hip/hip_runtime.h>
#include <math.h>

#define NB   8
#define NC   256
#define ND   64
#define NPIX 4096
#define LSTR 72   // attn P LDS row stride (bf16 elems)

typedef short bf16x8 __attribute__((ext_vector_type(8)));   // 8 bf16 (4 VGPRs)
typedef float f32x4  __attribute__((ext_vector_type(4)));
typedef float f32x16 __attribute__((ext_vector_type(16)));

static __device__ __forceinline__ ushort f2bf(float f) {
    uint u = __float_as_uint(f);
    u += 0x7fffu + ((u >> 16) & 1u);      // round-to-nearest-even
    return (ushort)(u >> 16);
}
static __device__ __forceinline__ float bf2f(ushort h) {
    return __uint_as_float(((uint)h) << 16);
}

// ---------------------------------------------------------------------------
// transpose_x: x[b][c][p] f32 -> xt_h/xt_l [b][p][256] bf16 hi/lo.
// ---------------------------------------------------------------------------
__global__ __launch_bounds__(256) void transpose_x(
    const float* __restrict__ x, ushort* __restrict__ xth, ushort* __restrict__ xtl)
{
    __shared__ float tile[64][68];
    const int t = threadIdx.x;
    const int p0 = blockIdx.x * 64, c0 = blockIdx.y * 64, b = blockIdx.z;

    const int cl = t >> 4, p4 = (t & 15) * 4;
    #pragma unroll
    for (int i = 0; i < 4; i++) {
        const int c = cl + 16 * i;
        *(float4*)&tile[c][p4] =
            *(const float4*)&x[((size_t)(b * NC + c0 + c)) * NPIX + p0 + p4];
    }
    __syncthreads();

    const int pl = t & 63, ch = t >> 6;
    float v[16];
    #pragma unroll
    for (int j = 0; j < 16; j++) v[j] = tile[ch * 16 + j][pl];
    ushort h[16], l[16];
    #pragma unroll
    for (int j = 0; j < 16; j++) {
        h[j] = f2bf(v[j]);
        l[j] = f2bf(v[j] - bf2f(h[j]));
    }
    const size_t o = ((size_t)(b * NPIX + p0 + pl)) * 256 + c0 + ch * 16;
    *(uint4*)&xth[o]     = *(uint4*)&h[0];
    *(uint4*)&xth[o + 8] = *(uint4*)&h[8];
    *(uint4*)&xtl[o]     = *(uint4*)&l[0];
    *(uint4*)&xtl[o + 8] = *(uint4*)&l[8];
}

// ---------------------------------------------------------------------------
// transpose_w: W[co][ci][3][3] f32 -> wt[rs][co][ci] bf16 (hi/lo for q,k).
// ---------------------------------------------------------------------------
__global__ __launch_bounds__(256) void transpose_w(
    const float* __restrict__ Wq, const float* __restrict__ Wk,
    const float* __restrict__ Wv,
    ushort* __restrict__ qh, ushort* __restrict__ ql,
    ushort* __restrict__ kh, ushort* __restrict__ kl,
    ushort* __restrict__ vh)
{
    __shared__ float wb[2304];
    const int g = blockIdx.x, t = threadIdx.x;
    const float* src;
    ushort *dh, *dl;
    int co, Co, split;
    if (g < 64)       { src = Wq + (size_t)g * 2304; co = g;       Co = 64;  dh = qh; dl = ql; split = 1; }
    else if (g < 128) { src = Wk + (size_t)(g - 64) * 2304; co = g - 64; Co = 64; dh = kh; dl = kl; split = 1; }
    else              { src = Wv + (size_t)(g - 128) * 2304; co = g - 128; Co = 256; dh = vh; dl = nullptr; split = 0; }

    for (int i = t; i < 2304; i += 256) wb[i] = src[i];
    __syncthreads();
    for (int j = t; j < 2304; j += 256) {
        const int rs = j >> 8, ci = j & 255;
        const float v = wb[ci * 9 + rs];
        const ushort hv = f2bf(v);
        const size_t o = ((size_t)(rs * Co + co)) * 256 + ci;
        dh[o] = hv;
        if (split) dl[o] = f2bf(v - bf2f(hv));
    }
}

// ---------------------------------------------------------------------------
// MFMA conv (q/k, split-bf16 3-term). R2 structure (proven, no spills).
// Block = 64co x 256pix (4 rows), wave=row. ci-chunk 16, ci padded to 24.
// grid (16 hq, 8 b, 2 {q,k}), dyn LDS 65920 B.
// ---------------------------------------------------------------------------
__global__ __launch_bounds__(256) void conv_split_k(
    const ushort* __restrict__ xth, const ushort* __restrict__ xtl,
    const ushort* __restrict__ wqh, const ushort* __restrict__ wql,
    const ushort* __restrict__ wkh, const ushort* __restrict__ wkl,
    const float* __restrict__ bq, const float* __restrict__ bk,
    ushort* __restrict__ qoh, ushort* __restrict__ qol,
    ushort* __restrict__ koh, ushort* __restrict__ kol)
{
    extern __shared__ char smem[];
    ushort* xsh = (ushort*)smem;                 // [6][66][24]
    ushort* xsl = xsh + 6 * 66 * 24;             // [6][66][24]
    ushort* wsp = xsl + 6 * 66 * 24;             // [9][64][24] (one w-plane at a time)
    float*  sbias = (float*)(wsp + 9 * 64 * 24); // [64]

    const int hq = blockIdx.x, b = blockIdx.y, ct = blockIdx.z;
    const ushort* wth = ct ? wkh : wqh;
    const ushort* wtl = ct ? wkl : wql;
    const float*  bias = ct ? bk : bq;
    ushort* outh = ct ? koh : qoh;
    ushort* outl = ct ? kol : qol;

    const int t = threadIdx.x;
    const int wv = t >> 6, lane = t & 63;
    const int l31 = lane & 31, khl = lane >> 5;
    const int lanebase = l31 * 24 + khl * 8;
    const int h = hq * 4 + wv;

    if (t < 64) sbias[t] = bias[t];
    for (int i = t; i < 384; i += 256) {
        const int p = i / 192, r2 = i % 192;
        const int row = r2 / 32, e = (r2 % 32) / 16, ci = r2 & 15;
        (p ? xsl : xsh)[(row * 66 + e * 65) * 24 + ci] = 0;
    }

    f32x16 a00 = {0}, a01 = {0}, a10 = {0}, a11 = {0};  // [ms(co)][ns(pix)]

    for (int ch = 0; ch < 16; ch++) {
        __syncthreads();
        const int ci0 = ch * 16;
        #pragma unroll
        for (int pl2 = 0; pl2 < 2; pl2++) {
            const ushort* src = pl2 ? xtl : xth;
            ushort* dst = pl2 ? xsl : xsh;
            #pragma unroll
            for (int i = 0; i < 3; i++) {
                const int a = i * 256 + t;
                const int cih = a & 1, col = (a >> 1) & 63, row = a >> 7;
                const int hs = hq * 4 + row - 1;
                uint4 val = {0, 0, 0, 0};
                if (hs >= 0 && hs < 64)
                    val = *(const uint4*)&src[((size_t)(b * NPIX + hs * 64 + col)) * 256 + ci0 + cih * 8];
                *(uint4*)&dst[(row * 66 + 1 + col) * 24 + cih * 8] = val;
            }
        }
        #pragma unroll
        for (int i = 0; i < 5; i++) {
            const int a = i * 256 + t;
            if (a < 1152) {
                const int cih = a & 1, co = (a >> 1) & 63, rs = a >> 7;
                uint4 wv4 = *(const uint4*)&wth[((size_t)(rs * 64 + co)) * 256 + ci0 + cih * 8];
                *(uint4*)&wsp[(rs * 64 + co) * 24 + cih * 8] = wv4;
            }
        }
        __syncthreads();
        // pass0: (wh.xh) + (wh.xl)
        #pragma unroll
        for (int rs = 0; rs < 9; rs++) {
            const int r = rs / 3, s = rs % 3;
            bf16x8 A0 = *(const bf16x8*)&wsp[rs * 1536 + lanebase];
            bf16x8 A1 = *(const bf16x8*)&wsp[rs * 1536 + 768 + lanebase];
            const int xo = ((wv + r) * 66 + s) * 24 + lanebase;
            bf16x8 B0h = *(const bf16x8*)&xsh[xo];
            bf16x8 B1h = *(const bf16x8*)&xsh[xo + 768];
            bf16x8 B0l = *(const bf16x8*)&xsl[xo];
            bf16x8 B1l = *(const bf16x8*)&xsl[xo + 768];
            a00 = __builtin_amdgcn_mfma_f32_32x32x16_bf16(A0, B0h, a00, 0, 0, 0);
            a01 = __builtin_amdgcn_mfma_f32_32x32x16_bf16(A0, B1h, a01, 0, 0, 0);
            a10 = __builtin_amdgcn_mfma_f32_32x32x16_bf16(A1, B0h, a10, 0, 0, 0);
            a11 = __builtin_amdgcn_mfma_f32_32x32x16_bf16(A1, B1h, a11, 0, 0, 0);
            a00 = __builtin_amdgcn_mfma_f32_32x32x16_bf16(A0, B0l, a00, 0, 0, 0);
            a01 = __builtin_amdgcn_mfma_f32_32x32x16_bf16(A0, B1l, a01, 0, 0, 0);
            a10 = __builtin_amdgcn_mfma_f32_32x32x16_bf16(A1, B0l, a10, 0, 0, 0);
            a11 = __builtin_amdgcn_mfma_f32_32x32x16_bf16(A1, B1l, a11, 0, 0, 0);
        }
        __syncthreads();
        #pragma unroll
        for (int i = 0; i < 5; i++) {
            const int a = i * 256 + t;
            if (a < 1152) {
                const int cih = a & 1, co = (a >> 1) & 63, rs = a >> 7;
                uint4 wv4 = *(const uint4*)&wtl[((size_t)(rs * 64 + co)) * 256 + ci0 + cih * 8];
                *(uint4*)&wsp[(rs * 64 + co) * 24 + cih * 8] = wv4;
            }
        }
        __syncthreads();
        // pass1: (wl.xh)
        #pragma unroll
        for (int rs = 0; rs < 9; rs++) {
            const int r = rs / 3, s = rs % 3;
            bf16x8 A0 = *(const bf16x8*)&wsp[rs * 1536 + lanebase];
            bf16x8 A1 = *(const bf16x8*)&wsp[rs * 1536 + 768 + lanebase];
            const int xo = ((wv + r) * 66 + s) * 24 + lanebase;
            bf16x8 B0h = *(const bf16x8*)&xsh[xo];
            bf16x8 B1h = *(const bf16x8*)&xsh[xo + 768];
            a00 = __builtin_amdgcn_mfma_f32_32x32x16_bf16(A0, B0h, a00, 0, 0, 0);
            a01 = __builtin_amdgcn_mfma_f32_32x32x16_bf16(A0, B1h, a01, 0, 0, 0);
            a10 = __builtin_amdgcn_mfma_f32_32x32x16_bf16(A1, B0h, a10, 0, 0, 0);
            a11 = __builtin_amdgcn_mfma_f32_32x32x16_bf16(A1, B1h, a11, 0, 0, 0);
        }
    }

    const float4* sb4 = (const float4*)sbias;
    #pragma unroll
    for (int ms = 0; ms < 2; ms++)
        #pragma unroll
        for (int ns = 0; ns < 2; ns++) {
            const f32x16 av = ms ? (ns ? a11 : a10) : (ns ? a01 : a00);
            const int p = h * 64 + ns * 32 + l31;
            #pragma unroll
            for (int g = 0; g < 4; g++) {
                const float4 bi = sb4[ms * 8 + 2 * g + khl];
                float v0 = av[4 * g + 0] + bi.x;
                float v1 = av[4 * g + 1] + bi.y;
                float v2 = av[4 * g + 2] + bi.z;
                float v3 = av[4 * g + 3] + bi.w;
                ushort4 hv, lv;
                hv.x = f2bf(v0); lv.x = f2bf(v0 - bf2f(hv.x));
                hv.y = f2bf(v1); lv.y = f2bf(v1 - bf2f(hv.y));
                hv.z = f2bf(v2); lv.z = f2bf(v2 - bf2f(hv.z));
                hv.w = f2bf(v3); lv.w = f2bf(v3 - bf2f(hv.w));
                const size_t o = ((size_t)(b * NPIX + p)) * 64 + ms * 32 + 8 * g + 4 * khl;
                *(ushort4*)&outh[o] = hv;
                *(ushort4*)&outl[o] = lv;
            }
        }
}

// ---------------------------------------------------------------------------
// MFMA conv (v, plain bf16). R2 structure. A = x (m=pixel), B = w (n=co).
// grid (16 hq, 8 b, 4 cotile), dyn LDS 46912 B.
// ---------------------------------------------------------------------------
__global__ __launch_bounds__(256) void conv_v_k(
    const ushort* __restrict__ xth, const ushort* __restrict__ wtv,
    const float* __restrict__ bv, ushort* __restrict__ vout)
{
    extern __shared__ char smem[];
    ushort* xsh = (ushort*)smem;                 // [6][66][24]
    ushort* wsp = xsh + 6 * 66 * 24;             // [9][64][24]
    float*  sbias = (float*)(wsp + 9 * 64 * 24); // [64]

    const int hq = blockIdx.x, b = blockIdx.y, co0 = blockIdx.z * 64;
    const int t = threadIdx.x;
    const int wv = t >> 6, lane = t & 63;
    const int l31 = lane & 31, khl = lane >> 5;
    const int lanebase = l31 * 24 + khl * 8;
    const int h = hq * 4 + wv;

    if (t < 64) sbias[t] = bv[co0 + t];
    for (int i = t; i < 192; i += 256) {
        const int row = i / 32, e = (i % 32) / 16, ci = i & 15;
        xsh[(row * 66 + e * 65) * 24 + ci] = 0;
    }

    f32x16 a00 = {0}, a01 = {0}, a10 = {0}, a11 = {0};  // [ms(pix)][ns(co)]

    for (int ch = 0; ch < 16; ch++) {
        __syncthreads();
        const int ci0 = ch * 16;
        #pragma unroll
        for (int i = 0; i < 3; i++) {
            const int a = i * 256 + t;
            const int cih = a & 1, col = (a >> 1) & 63, row = a >> 7;
            const int hs = hq * 4 + row - 1;
            uint4 val = {0, 0, 0, 0};
            if (hs >= 0 && hs < 64)
                val = *(const uint4*)&xth[((size_t)(b * NPIX + hs * 64 + col)) * 256 + ci0 + cih * 8];
            *(uint4*)&xsh[(row * 66 + 1 + col) * 24 + cih * 8] = val;
        }
        #pragma unroll
        for (int i = 0; i < 5; i++) {
            const int a = i * 256 + t;
            if (a < 1152) {
                const int cih = a & 1, co = (a >> 1) & 63, rs = a >> 7;
                uint4 wv4 = *(const uint4*)&wtv[((size_t)(rs * 256 + co0 + co)) * 256 + ci0 + cih * 8];
                *(uint4*)&wsp[(rs * 64 + co) * 24 + cih * 8] = wv4;
            }
        }
        __syncthreads();
        #pragma unroll
        for (int rs = 0; rs < 9; rs++) {
            const int r = rs / 3, s = rs % 3;
            const int xo = ((wv + r) * 66 + s) * 24 + lanebase;
            bf16x8 A0 = *(const bf16x8*)&xsh[xo];
            bf16x8 A1 = *(const bf16x8*)&xsh[xo + 768];
            bf16x8 B0 = *(const bf16x8*)&wsp[rs * 1536 + lanebase];
            bf16x8 B1 = *(const bf16x8*)&wsp[rs * 1536 + 768 + lanebase];
            a00 = __builtin_amdgcn_mfma_f32_32x32x16_bf16(A0, B0, a00, 0, 0, 0);
            a01 = __builtin_amdgcn_mfma_f32_32x32x16_bf16(A0, B1, a01, 0, 0, 0);
            a10 = __builtin_amdgcn_mfma_f32_32x32x16_bf16(A1, B0, a10, 0, 0, 0);
            a11 = __builtin_amdgcn_mfma_f32_32x32x16_bf16(A1, B1, a11, 0, 0, 0);
        }
    }

    #pragma unroll
    for (int ns = 0; ns < 2; ns++) {
        const int co = co0 + ns * 32 + l31;
        const float bi = sbias[ns * 32 + l31];
        #pragma unroll
        for (int ms = 0; ms < 2; ms++) {
            const f32x16 av = ms ? (ns ? a11 : a10) : (ns ? a01 : a00);
            #pragma unroll
            for (int g = 0; g < 4; g++) {
                const int p = h * 64 + ms * 32 + 8 * g + 4 * khl;
                ushort4 ov;
                ov.x = f2bf(av[4 * g + 0] + bi);
                ov.y = f2bf(av[4 * g + 1] + bi);
                ov.z = f2bf(av[4 * g + 2] + bi);
                ov.w = f2bf(av[4 * g + 3] + bi);
                *(ushort4*)&vout[((size_t)(b * NC + co)) * NPIX + p] = ov;
            }
        }
    }
}

// ---------------------------------------------------------------------------
// MFMA flash attention v4. grid 512 1-D (b = id&7 -> XCD pin), block 256.
// v3 layout + P double-buffered (ONE barrier/iter) + K/V register prefetch
// one iter ahead (K reloaded right after QK, V right after PV -> L2 latency
// hidden under MFMA). LDS ~20 KB.
// ---------------------------------------------------------------------------
__global__ __launch_bounds__(256, 2) void attn_k(
    const ushort* __restrict__ qh, const ushort* __restrict__ ql,
    const ushort* __restrict__ kh, const ushort* __restrict__ kl,
    const ushort* __restrict__ vb, const float* __restrict__ x,
    float* __restrict__ out)
{
    const int id = blockIdx.x;
    const int b  = id & 7;
    const int m0 = (id >> 3) * 64;
    const int t  = threadIdx.x;
    const int w  = t >> 6;
    const int lane = t & 63;
    const int quad = lane >> 4;
    const int l16  = lane & 15;

    __shared__ ushort sps[2][64 * LSTR];   // P double buffer
    __shared__ float  red[4][64];
    __shared__ float  ivl[64];

    // hoisted Q B-frags: B[col=m=l16][k=d]
    bf16x8 aqh[4][2], aql[4][2];
    #pragma unroll
    for (int mg = 0; mg < 4; mg++)
        #pragma unroll
        for (int ks = 0; ks < 2; ks++) {
            const size_t g = ((size_t)b * NPIX + m0 + mg * 16 + l16) * ND + ks * 32 + quad * 8;
            aqh[mg][ks] = *(const bf16x8*)&qh[g];
            aql[mg][ks] = *(const bf16x8*)&ql[g];
        }

    // per-wave base offsets
    const size_t kbase = ((size_t)b * NPIX + 16 * w + l16) * ND + quad * 8;   // + n0*ND + ks*32
    size_t vbase[4];
    #pragma unroll
    for (int ct = 0; ct < 4; ct++)
        vbase[ct] = ((size_t)b * NC + 64 * w + ct * 16 + l16) * NPIX + quad * 8;  // + n0 + ks*32

    // preload K/V frags for n0 = 0
    bf16x8 kfh[2], kfl[2], vf[4][2];
    #pragma unroll
    for (int ks = 0; ks < 2; ks++) {
        kfh[ks] = *(const bf16x8*)&kh[kbase + ks * 32];
        kfl[ks] = *(const bf16x8*)&kl[kbase + ks * 32];
    }
    #pragma unroll
    for (int ct = 0; ct < 4; ct++)
        #pragma unroll
        for (int ks = 0; ks < 2; ks++)
            vf[ct][ks] = *(const bf16x8*)&vb[vbase[ct] + ks * 32];

    f32x4 acc[4][4];
    #pragma unroll
    for (int i = 0; i < 4; i++)
        #pragma unroll
        for (int j = 0; j < 4; j++) acc[i][j] = (f32x4){0.f, 0.f, 0.f, 0.f};
    float lsum[4] = {0.f, 0.f, 0.f, 0.f};

    for (int n0 = 0; n0 < NPIX; n0 += 64) {
        const int buf = (n0 >> 6) & 1;
        const bool nxt = (n0 + 64) < NPIX;

        // ---- QK (S^T = K.Q^T), exp, pack -> sps[buf] ----
        #pragma unroll
        for (int mg = 0; mg < 4; mg++) {
            f32x4 s = {0.f, 0.f, 0.f, 0.f};
            #pragma unroll
            for (int ks = 0; ks < 2; ks++) {
                s = __builtin_amdgcn_mfma_f32_16x16x32_bf16(kfh[ks], aqh[mg][ks], s, 0, 0, 0);
                s = __builtin_amdgcn_mfma_f32_16x16x32_bf16(kfl[ks], aqh[mg][ks], s, 0, 0, 0);
                s = __builtin_amdgcn_mfma_f32_16x16x32_bf16(kfh[ks], aql[mg][ks], s, 0, 0, 0);
            }
            uint2 pk;
            {
                const ushort p0 = f2bf(__expf(s[0] - 30.f));
                const ushort p1 = f2bf(__expf(s[1] - 30.f));
                const ushort p2 = f2bf(__expf(s[2] - 30.f));
                const ushort p3 = f2bf(__expf(s[3] - 30.f));
                lsum[mg] += (bf2f(p0) + bf2f(p1)) + (bf2f(p2) + bf2f(p3));
                pk.x = (uint)p0 | ((uint)p1 << 16);
                pk.y = (uint)p2 | ((uint)p3 << 16);
            }
            *(uint2*)&sps[buf][(mg * 16 + l16) * LSTR + 16 * w + quad * 4] = pk;
        }

        // K prefetch for n0+64 (kf dead after QK; lands during barrier+PV)
        if (nxt) {
            const size_t kb = kbase + (size_t)(n0 + 64) * ND;
            #pragma unroll
            for (int ks = 0; ks < 2; ks++) {
                kfh[ks] = *(const bf16x8*)&kh[kb + ks * 32];
                kfl[ks] = *(const bf16x8*)&kl[kb + ks * 32];
            }
        }
        __syncthreads();   // P[buf] visible (single barrier per iter; dbuf)

        // ---- PV: A = P frags (LDS), B = V frags (regs) ----
        #pragma unroll
        for (int ks = 0; ks < 2; ks++) {
            bf16x8 ap[4];
            #pragma unroll
            for (int mg = 0; mg < 4; mg++)
                ap[mg] = *(const bf16x8*)&sps[buf][(mg * 16 + l16) * LSTR + ks * 32 + quad * 8];
            #pragma unroll
            for (int mg = 0; mg < 4; mg++)
                #pragma unroll
                for (int ct = 0; ct < 4; ct++)
                    acc[mg][ct] = __builtin_amdgcn_mfma_f32_16x16x32_bf16(
                        ap[mg], vf[ct][ks], acc[mg][ct], 0, 0, 0);
        }

        // V prefetch for n0+64 (vf dead after PV; lands during next QK+exp)
        if (nxt) {
            #pragma unroll
            for (int ct = 0; ct < 4; ct++)
                #pragma unroll
                for (int ks = 0; ks < 2; ks++)
                    vf[ct][ks] = *(const bf16x8*)&vb[vbase[ct] + n0 + 64 + ks * 32];
        }
    }

    // rowsum: reduce across quad lanes, then across the 4 nt-waves via LDS
    #pragma unroll
    for (int mg = 0; mg < 4; mg++) {
        lsum[mg] += __shfl_xor(lsum[mg], 16, 64);
        lsum[mg] += __shfl_xor(lsum[mg], 32, 64);
    }
    if (quad == 0) {
        #pragma unroll
        for (int mg = 0; mg < 4; mg++) red[w][mg * 16 + l16] = lsum[mg];
    }
    __syncthreads();
    if (t < 64)
        ivl[t] = 1.f / (red[0][t] + red[1][t] + red[2][t] + red[3][t]);
    __syncthreads();

    // epilogue: out = acc/l + x; D rows m = mg*16+quad*4+r, col c = l16
    #pragma unroll
    for (int mg = 0; mg < 4; mg++) {
        const int mrow = mg * 16 + quad * 4;
        const float4 il4 = *(const float4*)&ivl[mrow];
        const int m = m0 + mrow;
        #pragma unroll
        for (int ct = 0; ct < 4; ct++) {
            const int c = 64 * w + ct * 16 + l16;
            const size_t base = ((size_t)b * NC + c) * NPIX + m;
            const float4 xv = *(const float4*)&x[base];
            const f32x4 a = acc[mg][ct];
            float4 o;
            o.x = fmaf(a[0], il4.x, xv.x);
            o.y = fmaf(a[1], il4.y, xv.y);
            o.z = fmaf(a[2], il4.z, xv.z);
            o.w = fmaf(a[3], il4.w, xv.w);
            *(float4*)&out[base] = o;
        }
    }
}

extern "C" void kernel_launch(void* const* d_in, const int* in_sizes, int n_in,
                              void* d_out, int out_size, void* d_ws, size_t ws_size,
                              hipStream_t stream)
{
    const float* x  = (const float*)d_in[0];
    const float* Wq = (const float*)d_in[1];
    const float* bq = (const float*)d_in[2];
    const float* Wk = (const float*)d_in[3];
    const float* bk = (const float*)d_in[4];
    const float* Wv = (const float*)d_in[5];
    const float* bv = (const float*)d_in[6];
    float* outp = (float*)d_out;

    const size_t XT = (size_t)NB * NPIX * 256;   // 8,388,608
    const size_t QK = (size_t)NB * NPIX * ND;    // 2,097,152
    ushort* xt_h = (ushort*)d_ws;
    ushort* xt_l = xt_h + XT;
    ushort* v_b  = xt_l;              // alias: conv_v (after conv_split) overwrites xt_l
    ushort* q_h  = xt_l + XT;
    ushort* q_l  = q_h + QK;
    ushort* k_h  = q_l + QK;
    ushort* k_l  = k_h + QK;
    ushort* wtq_h = k_l + QK;         // 9*64*256 = 147456 each
    ushort* wtq_l = wtq_h + 147456;
    ushort* wtk_h = wtq_l + 147456;
    ushort* wtk_l = wtk_h + 147456;
    ushort* wtv_h = wtk_l + 147456;   // 9*256*256 = 589824

    dim3 blk(256);
    transpose_x<<<dim3(64, 4, NB), blk, 0, stream>>>(x, xt_h, xt_l);
    transpose_w<<<dim3(384), blk, 0, stream>>>(Wq, Wk, Wv, wtq_h, wtq_l, wtk_h, wtk_l, wtv_h);
    conv_split_k<<<dim3(16, NB, 2), blk, 65920, stream>>>(
        xt_h, xt_l, wtq_h, wtq_l, wtk_h, wtk_l, bq, bk, q_h, q_l, k_h, k_l);
    conv_v_k<<<dim3(16, NB, 4), blk, 46912, stream>>>(xt_h, wtv_h, bv, v_b);
    attn_k<<<dim3(512), blk, 0, stream>>>(q_h, q_l, k_h, k_l, v_b, x, outp);
}